// Round 1
// baseline (4384.640 us; speedup 1.0000x reference)
//
#include <hip/hip_runtime.h>
#include <hip/hip_cooperative_groups.h>

namespace cg = cooperative_groups;

typedef unsigned short u16;
typedef unsigned int u32;
using bfrag = __attribute__((ext_vector_type(8))) short;   // 8 bf16 (4 VGPRs)
using facc  = __attribute__((ext_vector_type(4))) float;   // MFMA accumulator

#define DEV __device__ __forceinline__

DEV u16 f2bf(float f) {
    u32 u = __float_as_uint(f);
    u32 r = (u + 0x7FFFu + ((u >> 16) & 1u)) >> 16;   // RNE
    return (u16)r;
}
DEV float bf2f(u16 h) { return __uint_as_float(((u32)h) << 16); }
DEV u32 pk2(float a, float b) { return (u32)f2bf(a) | ((u32)f2bf(b) << 16); }
DEV float sigm(float x) { return 1.0f / (1.0f + __expf(-x)); }
DEV float tanh2(float x) { return 2.0f * sigm(2.0f * x) - 1.0f; }  // overflow-safe tanh
DEV facc mfma16(bfrag a, bfrag b, facc c) {
    return __builtin_amdgcn_mfma_f32_16x16x32_bf16(a, b, c, 0, 0, 0);
}

// ---------------- prologue / weight-prep kernels ----------------

// dst[n*K + k] = src[k*N + n]  (bf16 out), K = 1<<lgK
__global__ void prep_transpose(const float* __restrict__ src, u16* __restrict__ dst,
                               int lgK, int N) {
    int K = 1 << lgK;
    int total = K * N;
    for (int i = blockIdx.x * blockDim.x + threadIdx.x; i < total; i += gridDim.x * blockDim.x) {
        int n = i >> lgK, k = i & (K - 1);
        dst[i] = f2bf(src[k * N + n]);
    }
}

// UVpk[p][k]: p = gate-interleaved packed col (j*4+g <-> orig col g*256+j), k<256 -> U row k, k>=256 -> V row k-256
__global__ void prep_uvpack(const float* __restrict__ U, const float* __restrict__ V,
                            u16* __restrict__ dst) {
    for (int i = blockIdx.x * blockDim.x + threadIdx.x; i < 1024 * 512; i += gridDim.x * blockDim.x) {
        int p = i >> 9, k = i & 511;
        int j = p >> 2, g = p & 3;
        float v = (k < 256) ? U[k * 1024 + g * 256 + j] : V[(k - 256) * 1024 + g * 256 + j];
        dst[i] = f2bf(v);
    }
}

// Wpk[p][k] = W[k][g*256+j] (gate-interleaved), bpk[p] = b[g*256+j]
__global__ void prep_wpack(const float* __restrict__ W, const float* __restrict__ b,
                           u16* __restrict__ dst, float* __restrict__ bpk) {
    for (int i = blockIdx.x * blockDim.x + threadIdx.x; i < 1024 * 256; i += gridDim.x * blockDim.x) {
        int p = i >> 8, k = i & 255;
        int j = p >> 2, g = p & 3;
        dst[i] = f2bf(W[k * 1024 + g * 256 + j]);
        if (k == 0) bpk[p] = b[g * 256 + j];
    }
}

// FW[k][c] = sum_j late0_w[k][j]*late1_w[j][c];  fb[c] = late0_b@late1_w + late1_b
__global__ void prep_final(const float* __restrict__ l0w, const float* __restrict__ l0b,
                           const float* __restrict__ l1w, const float* __restrict__ l1b,
                           float* __restrict__ FW, float* __restrict__ fb) {
    int tid = threadIdx.x;
    for (int idx = tid; idx < 1024; idx += 256) {
        int k = idx >> 1, c = idx & 1;
        float a = 0.f;
        for (int j = 0; j < 256; ++j) a += l0w[k * 256 + j] * l1w[j * 2 + c];
        FW[idx] = a;
    }
    if (tid < 2) {
        float a = l1b[tid];
        for (int j = 0; j < 256; ++j) a += l0b[j] * l1w[j * 2 + tid];
        fb[tid] = a;
    }
}

// ---------------- big GEMMs (phase A) ----------------
// G1: C_bf16[6400][256] = A_f32[6400][2048] @ BT_bf16[256][2048]^T + bias. Tile 64x128.
__global__ __launch_bounds__(256) void gemm_g1(
    const float* __restrict__ A0, const float* __restrict__ A1,
    const u16* __restrict__ B0, const u16* __restrict__ B1,
    const float* __restrict__ bias0, const float* __restrict__ bias1,
    u16* __restrict__ C0, u16* __restrict__ C1) {
    const int K = 2048;
    int zs = blockIdx.z;
    const float* A = zs ? A1 : A0;
    const u16* BT = zs ? B1 : B0;
    const float* bias = zs ? bias1 : bias0;
    u16* C = zs ? C1 : C0;
    int m0 = blockIdx.x * 64, n0 = blockIdx.y * 128;
    __shared__ __align__(16) u16 Al[64 * 72];
    __shared__ __align__(16) u16 Bl[128 * 72];
    int tid = threadIdx.x, w = tid >> 6, l = tid & 63, lm = l & 15, kh = l >> 4;
    int arow = tid >> 2, aseg = tid & 3;   // A: 64 rows x 16 floats
    int brow = tid >> 1, bseg = tid & 1;   // B: 128 rows x 32 bf16
    facc acc[8];
#pragma unroll
    for (int i = 0; i < 8; ++i) acc[i] = (facc){0.f, 0.f, 0.f, 0.f};
    for (int c = 0; c < 32; ++c) {
        float4 av[4];
#pragma unroll
        for (int u = 0; u < 4; ++u)
            av[u] = *(const float4*)&A[(size_t)(m0 + arow) * K + c * 64 + aseg * 16 + u * 4];
        uint4 bv[4];
#pragma unroll
        for (int u = 0; u < 4; ++u)
            bv[u] = *(const uint4*)&BT[(size_t)(n0 + brow) * K + c * 64 + bseg * 32 + u * 8];
        __syncthreads();
        u32 pk[8];
#pragma unroll
        for (int u = 0; u < 4; ++u) {
            pk[2 * u] = pk2(av[u].x, av[u].y);
            pk[2 * u + 1] = pk2(av[u].z, av[u].w);
        }
        *(uint4*)&Al[arow * 72 + aseg * 16] = make_uint4(pk[0], pk[1], pk[2], pk[3]);
        *(uint4*)&Al[arow * 72 + aseg * 16 + 8] = make_uint4(pk[4], pk[5], pk[6], pk[7]);
#pragma unroll
        for (int u = 0; u < 4; ++u)
            *(uint4*)&Bl[brow * 72 + bseg * 32 + u * 8] = bv[u];
        __syncthreads();
#pragma unroll
        for (int ks = 0; ks < 2; ++ks) {
            bfrag a = *(const bfrag*)&Al[(16 * w + lm) * 72 + ks * 32 + kh * 8];
#pragma unroll
            for (int tt = 0; tt < 8; ++tt) {
                bfrag bb = *(const bfrag*)&Bl[(tt * 16 + lm) * 72 + ks * 32 + kh * 8];
                acc[tt] = mfma16(a, bb, acc[tt]);
            }
        }
    }
#pragma unroll
    for (int tt = 0; tt < 8; ++tt) {
        int col = n0 + tt * 16 + lm;
        float bs = bias[col];
#pragma unroll
        for (int j = 0; j < 4; ++j) {
            int m = m0 + 16 * w + 4 * kh + j;
            C[(size_t)m * 256 + col] = f2bf(acc[tt][j] + bs);
        }
    }
}

// G2: Wx_bf16[t*256+b][1024] = xv_bf16[6400][256] @ Wpk[1024][256]^T + bpk (row remap b*25+t -> t*256+b)
__global__ __launch_bounds__(256) void gemm_g2(
    const u16* __restrict__ A0, const u16* __restrict__ A1,
    const u16* __restrict__ B0, const u16* __restrict__ B1,
    const float* __restrict__ bp0, const float* __restrict__ bp1,
    u16* __restrict__ O0, u16* __restrict__ O1) {
    const int K = 256;
    int zs = blockIdx.z;
    const u16* A = zs ? A1 : A0;
    const u16* BT = zs ? B1 : B0;
    const float* bpk = zs ? bp1 : bp0;
    u16* O = zs ? O1 : O0;
    int m0 = blockIdx.x * 64, n0 = blockIdx.y * 128;
    __shared__ __align__(16) u16 Al[64 * 72];
    __shared__ __align__(16) u16 Bl[128 * 72];
    int tid = threadIdx.x, w = tid >> 6, l = tid & 63, lm = l & 15, kh = l >> 4;
    int arow = tid >> 2, aseg = tid & 3;
    int brow = tid >> 1, bseg = tid & 1;
    facc acc[8];
#pragma unroll
    for (int i = 0; i < 8; ++i) acc[i] = (facc){0.f, 0.f, 0.f, 0.f};
    for (int c = 0; c < 4; ++c) {
        uint4 av[2];
#pragma unroll
        for (int u = 0; u < 2; ++u)
            av[u] = *(const uint4*)&A[(size_t)(m0 + arow) * K + c * 64 + aseg * 16 + u * 8];
        uint4 bv[4];
#pragma unroll
        for (int u = 0; u < 4; ++u)
            bv[u] = *(const uint4*)&BT[(size_t)(n0 + brow) * K + c * 64 + bseg * 32 + u * 8];
        __syncthreads();
#pragma unroll
        for (int u = 0; u < 2; ++u)
            *(uint4*)&Al[arow * 72 + aseg * 16 + u * 8] = av[u];
#pragma unroll
        for (int u = 0; u < 4; ++u)
            *(uint4*)&Bl[brow * 72 + bseg * 32 + u * 8] = bv[u];
        __syncthreads();
#pragma unroll
        for (int ks = 0; ks < 2; ++ks) {
            bfrag a = *(const bfrag*)&Al[(16 * w + lm) * 72 + ks * 32 + kh * 8];
#pragma unroll
            for (int tt = 0; tt < 8; ++tt) {
                bfrag bb = *(const bfrag*)&Bl[(tt * 16 + lm) * 72 + ks * 32 + kh * 8];
                acc[tt] = mfma16(a, bb, acc[tt]);
            }
        }
    }
#pragma unroll
    for (int tt = 0; tt < 8; ++tt) {
        int col = n0 + tt * 16 + lm;
        float bs = bpk[col];
#pragma unroll
        for (int j = 0; j < 4; ++j) {
            int m = m0 + 16 * w + 4 * kh + j;
            int bi = m / 25, ti = m - bi * 25;
            O[(size_t)(ti * 256 + bi) * 1024 + col] = f2bf(acc[tt][j] + bs);
        }
    }
}

// ---------------- recurrent cooperative kernel ----------------

struct MarnArgs {
    const u16 *Wxv, *Wxt, *UVpk, *attT, *redT, *mabT;
    const float *att_b, *rvb, *rtb, *mob, *FW, *fb;
    float *cv, *ct, *psum;
    u16 *hv0, *hv1, *ht0, *ht1, *zz, *eh, *rvt;
    float* out;
};

__global__ __launch_bounds__(256) void marn_recur(MarnArgs P) {
    cg::grid_group grid = cg::this_grid();
    __shared__ __align__(16) unsigned char SM[31744];
    u16* Al = (u16*)SM;                       // [64][136] bf16 staging (A)
    u16* Bl = (u16*)(SM + 17408);             // [32][136] bf16 staging (B)
    float* sscr = (float*)SM;                 // [64][33] f32 epilogue scratch (aliases Al)
    float* ppart = (float*)(SM + 26112);      // 256 f32
    float* sinvl = (float*)(SM + 27136);      // 16 f32
    float* redscr = (float*)(SM + 27200);     // 4*16*17 f32
    int tid = threadIdx.x, w = tid >> 6, l = tid & 63, lm = l & 15, kh = l >> 4;
    int b = blockIdx.x;

    for (int t = 0; t < 25; ++t) {
        const u16* hvp = (t & 1) ? P.hv1 : P.hv0;
        const u16* htp = (t & 1) ? P.ht1 : P.ht0;
        u16* hvc = (t & 1) ? P.hv0 : P.hv1;
        u16* htc = (t & 1) ? P.ht0 : P.ht1;

        {   // ---- P1: s = Wx[t] + h@U + z@V -> gates -> c,h ----
            int m = b >> 6, n = b & 63;
            int r0 = m * 64, p0 = n * 32;
            bool sv = (n < 32);
            const u16* hsrc = sv ? hvp : htp;
            int arow = tid >> 2, aseg = tid & 3;
            int brow = tid >> 3, bseg = tid & 7;
            uint4 ar[2][4], br[2][2];
#pragma unroll
            for (int u = 0; u < 4; ++u)
                ar[0][u] = *(const uint4*)&hsrc[(r0 + arow) * 256 + aseg * 32 + u * 8];
#pragma unroll
            for (int u = 0; u < 2; ++u)
                br[0][u] = *(const uint4*)&P.UVpk[(p0 + brow) * 512 + bseg * 16 + u * 8];
            facc acc0 = (facc){0.f, 0.f, 0.f, 0.f}, acc1 = (facc){0.f, 0.f, 0.f, 0.f};
#pragma unroll
            for (int c = 0; c < 4; ++c) {
                int cb = c & 1;
                __syncthreads();
#pragma unroll
                for (int u = 0; u < 4; ++u)
                    *(uint4*)&Al[arow * 136 + aseg * 32 + u * 8] = ar[cb][u];
#pragma unroll
                for (int u = 0; u < 2; ++u)
                    *(uint4*)&Bl[brow * 136 + bseg * 16 + u * 8] = br[cb][u];
                __syncthreads();
                if (c < 3) {
                    int cn = c + 1, nb = cb ^ 1;
                    const u16* asrc = (cn < 2) ? hsrc : P.zz;
                    int koff = (cn & 1) * 128;
#pragma unroll
                    for (int u = 0; u < 4; ++u)
                        ar[nb][u] = *(const uint4*)&asrc[(r0 + arow) * 256 + koff + aseg * 32 + u * 8];
#pragma unroll
                    for (int u = 0; u < 2; ++u)
                        br[nb][u] = *(const uint4*)&P.UVpk[(p0 + brow) * 512 + cn * 128 + bseg * 16 + u * 8];
                }
#pragma unroll
                for (int ks = 0; ks < 4; ++ks) {
                    bfrag a = *(const bfrag*)&Al[(16 * w + lm) * 136 + ks * 32 + kh * 8];
                    bfrag b0 = *(const bfrag*)&Bl[lm * 136 + ks * 32 + kh * 8];
                    bfrag b1 = *(const bfrag*)&Bl[(16 + lm) * 136 + ks * 32 + kh * 8];
                    acc0 = mfma16(a, b0, acc0);
                    acc1 = mfma16(a, b1, acc1);
                }
            }
            __syncthreads();
#pragma unroll
            for (int j = 0; j < 4; ++j) {
                sscr[(16 * w + 4 * kh + j) * 33 + lm] = acc0[j];
                sscr[(16 * w + 4 * kh + j) * 33 + 16 + lm] = acc1[j];
            }
            __syncthreads();
            const u16* wxs = sv ? P.Wxv : P.Wxt;
            float* cptr = sv ? P.cv : P.ct;
            u16* hw = sv ? hvc : htc;
            int pl0 = sv ? p0 : (p0 - 1024);
#pragma unroll
            for (int it = 0; it < 2; ++it) {
                int item = tid + it * 256;
                int r = item >> 3, jl = item & 7;
                ushort4 wx = *(const ushort4*)&wxs[(size_t)(t * 256 + r0 + r) * 1024 + pl0 + jl * 4];
                float s0 = sscr[r * 33 + jl * 4 + 0] + bf2f(wx.x);
                float s1 = sscr[r * 33 + jl * 4 + 1] + bf2f(wx.y);
                float s2 = sscr[r * 33 + jl * 4 + 2] + bf2f(wx.z);
                float s3 = sscr[r * 33 + jl * 4 + 3] + bf2f(wx.w);
                float fg = sigm(s0), ig = sigm(s1), og = sigm(s2), ch = tanh2(s3);
                int jg = (pl0 >> 2) + jl;
                int ci = (r0 + r) * 256 + jg;
                float cnew = fg * cptr[ci] + ig * ch;
                cptr[ci] = cnew;
                hw[ci] = f2bf(tanh2(cnew) * og);
            }
        }
        grid.sync();

        if (t < 24) {
            {   // ---- P2: exp-logits (att), row-sums, eh = e * h_concat ----
                int m = b >> 6, n = b & 63;
                int r0 = m * 64, c0 = n * 32;
                int arow = tid >> 2, aseg = tid & 3;
                int brow = tid >> 3, bseg = tid & 7;
                uint4 ar[2][4], br[2][2];
#pragma unroll
                for (int u = 0; u < 4; ++u)
                    ar[0][u] = *(const uint4*)&hvc[(r0 + arow) * 256 + aseg * 32 + u * 8];
#pragma unroll
                for (int u = 0; u < 2; ++u)
                    br[0][u] = *(const uint4*)&P.attT[(c0 + brow) * 512 + bseg * 16 + u * 8];
                facc acc0 = (facc){0.f, 0.f, 0.f, 0.f}, acc1 = (facc){0.f, 0.f, 0.f, 0.f};
#pragma unroll
                for (int c = 0; c < 4; ++c) {
                    int cb = c & 1;
                    __syncthreads();
#pragma unroll
                    for (int u = 0; u < 4; ++u)
                        *(uint4*)&Al[arow * 136 + aseg * 32 + u * 8] = ar[cb][u];
#pragma unroll
                    for (int u = 0; u < 2; ++u)
                        *(uint4*)&Bl[brow * 136 + bseg * 16 + u * 8] = br[cb][u];
                    __syncthreads();
                    if (c < 3) {
                        int cn = c + 1, nb = cb ^ 1;
                        const u16* asrc = (cn < 2) ? hvc : htc;
                        int koff = (cn & 1) * 128;
#pragma unroll
                        for (int u = 0; u < 4; ++u)
                            ar[nb][u] = *(const uint4*)&asrc[(r0 + arow) * 256 + koff + aseg * 32 + u * 8];
#pragma unroll
                        for (int u = 0; u < 2; ++u)
                            br[nb][u] = *(const uint4*)&P.attT[(c0 + brow) * 512 + cn * 128 + bseg * 16 + u * 8];
                    }
#pragma unroll
                    for (int ks = 0; ks < 4; ++ks) {
                        bfrag a = *(const bfrag*)&Al[(16 * w + lm) * 136 + ks * 32 + kh * 8];
                        bfrag b0 = *(const bfrag*)&Bl[lm * 136 + ks * 32 + kh * 8];
                        bfrag b1 = *(const bfrag*)&Bl[(16 + lm) * 136 + ks * 32 + kh * 8];
                        acc0 = mfma16(a, b0, acc0);
                        acc1 = mfma16(a, b1, acc1);
                    }
                }
                __syncthreads();
#pragma unroll
                for (int j = 0; j < 4; ++j) {
                    sscr[(16 * w + 4 * kh + j) * 33 + lm] = acc0[j];
                    sscr[(16 * w + 4 * kh + j) * 33 + 16 + lm] = acc1[j];
                }
                __syncthreads();
                int r = tid >> 2, q = tid & 3;
                int n15 = n & 15;
                const u16* hfs = (n15 < 8) ? hvc : htc;
                int hc0 = (32 * n15) & 255;
                uint4 hfv = *(const uint4*)&hfs[(r0 + r) * 256 + hc0 + q * 8];
                const u16* hfp = (const u16*)&hfv;
                float ps = 0.f;
                u32 pk[4];
#pragma unroll
                for (int x = 0; x < 4; ++x) {
                    float e0 = __expf(sscr[r * 33 + q * 8 + 2 * x] + P.att_b[c0 + q * 8 + 2 * x]);
                    float e1 = __expf(sscr[r * 33 + q * 8 + 2 * x + 1] + P.att_b[c0 + q * 8 + 2 * x + 1]);
                    ps += e0 + e1;
                    pk[x] = (u32)f2bf(e0 * bf2f(hfp[2 * x])) | ((u32)f2bf(e1 * bf2f(hfp[2 * x + 1])) << 16);
                }
                *(uint4*)&P.eh[(size_t)(r0 + r) * 2048 + c0 + q * 8] = make_uint4(pk[0], pk[1], pk[2], pk[3]);
                ppart[r * 4 + q] = ps;
                __syncthreads();
                if (tid < 64) {
                    float s = ppart[tid * 4] + ppart[tid * 4 + 1] + ppart[tid * 4 + 2] + ppart[tid * 4 + 3];
                    P.psum[n * 256 + r0 + tid] = s;
                }
            }
            grid.sync();

            {   // ---- P3: rv|rt = relu(sinv * (eh-gather @ redT) + bias) ----
                int m = b >> 4, n = b & 15;
                int r0 = m * 16, nc0 = n * 32;
                int half = (n < 8) ? 0 : 1;
                if (tid < 64) {
                    int r = tid >> 2, q = tid & 3;
                    float s = 0.f;
                    for (int j2 = q * 16; j2 < q * 16 + 16; ++j2) s += P.psum[j2 * 256 + r0 + r];
                    ppart[r * 4 + q] = s;
                }
                __syncthreads();
                if (tid < 16)
                    sinvl[tid] = 1.0f / (ppart[tid * 4] + ppart[tid * 4 + 1] + ppart[tid * 4 + 2] + ppart[tid * 4 + 3]);
                int arow = tid >> 4, aseg = tid & 15;
                int brow = tid >> 3, bseg = tid & 7;
                uint4 ar[2], br[2][2];
                ar[0] = *(const uint4*)&P.eh[(size_t)(r0 + arow) * 2048 + half * 256 + aseg * 8];
#pragma unroll
                for (int u = 0; u < 2; ++u)
                    br[0][u] = *(const uint4*)&P.redT[(nc0 + brow) * 1024 + bseg * 16 + u * 8];
                int tt = w & 1, kh2 = w >> 1;
                facc acc = (facc){0.f, 0.f, 0.f, 0.f};
#pragma unroll
                for (int c = 0; c < 8; ++c) {
                    int cb = c & 1;
                    __syncthreads();
                    *(uint4*)&Al[arow * 136 + aseg * 8] = ar[cb];
#pragma unroll
                    for (int u = 0; u < 2; ++u)
                        *(uint4*)&Bl[brow * 136 + bseg * 16 + u * 8] = br[cb][u];
                    __syncthreads();
                    if (c < 7) {
                        int cn = c + 1, nb = cb ^ 1;
                        ar[nb] = *(const uint4*)&P.eh[(size_t)(r0 + arow) * 2048 + (cn >> 1) * 512 + half * 256 + (cn & 1) * 128 + aseg * 8];
#pragma unroll
                        for (int u = 0; u < 2; ++u)
                            br[nb][u] = *(const uint4*)&P.redT[(nc0 + brow) * 1024 + cn * 128 + bseg * 16 + u * 8];
                    }
#pragma unroll
                    for (int k2 = 0; k2 < 2; ++k2) {
                        int ks = kh2 * 2 + k2;
                        bfrag a = *(const bfrag*)&Al[lm * 136 + ks * 32 + kh * 8];
                        bfrag bb = *(const bfrag*)&Bl[(tt * 16 + lm) * 136 + ks * 32 + kh * 8];
                        acc = mfma16(a, bb, acc);
                    }
                }
                __syncthreads();
                if (w >= 2) {
#pragma unroll
                    for (int j = 0; j < 4; ++j)
                        redscr[tt * 272 + (4 * kh + j) * 17 + lm] = acc[j];
                }
                __syncthreads();
                if (w < 2) {
#pragma unroll
                    for (int j = 0; j < 4; ++j) {
                        float v = acc[j] + redscr[tt * 272 + (4 * kh + j) * 17 + lm];
                        int rloc = 4 * kh + j;
                        int col = nc0 + tt * 16 + lm;
                        float bs = (col < 256) ? P.rvb[col] : P.rtb[col - 256];
                        v = fmaxf(sinvl[rloc] * v + bs, 0.0f);
                        P.rvt[(r0 + rloc) * 512 + col] = f2bf(v);
                    }
                }
            }
            grid.sync();

            {   // ---- P4: z = [rv|rt] @ mab_out + b ----
                int m = b >> 4, n = b & 15;
                int r0 = m * 16, nc0 = n * 16;
                int arow = tid >> 4, aseg = tid & 15;
                uint4 ar[2], br[2];
                ar[0] = *(const uint4*)&P.rvt[(r0 + arow) * 512 + aseg * 8];
                br[0] = *(const uint4*)&P.mabT[(nc0 + arow) * 512 + aseg * 8];
                facc acc = (facc){0.f, 0.f, 0.f, 0.f};
#pragma unroll
                for (int c = 0; c < 4; ++c) {
                    int cb = c & 1;
                    __syncthreads();
                    *(uint4*)&Al[arow * 136 + aseg * 8] = ar[cb];
                    *(uint4*)&Bl[arow * 136 + aseg * 8] = br[cb];
                    __syncthreads();
                    if (c < 3) {
                        ar[cb ^ 1] = *(const uint4*)&P.rvt[(r0 + arow) * 512 + (c + 1) * 128 + aseg * 8];
                        br[cb ^ 1] = *(const uint4*)&P.mabT[(nc0 + arow) * 512 + (c + 1) * 128 + aseg * 8];
                    }
                    bfrag a = *(const bfrag*)&Al[lm * 136 + w * 32 + kh * 8];
                    bfrag bb = *(const bfrag*)&Bl[lm * 136 + w * 32 + kh * 8];
                    acc = mfma16(a, bb, acc);
                }
                __syncthreads();
                if (w > 0) {
#pragma unroll
                    for (int j = 0; j < 4; ++j)
                        redscr[(w - 1) * 272 + (4 * kh + j) * 17 + lm] = acc[j];
                }
                __syncthreads();
                if (w == 0) {
#pragma unroll
                    for (int j = 0; j < 4; ++j) {
                        int idx = (4 * kh + j) * 17 + lm;
                        float v = acc[j] + redscr[idx] + redscr[272 + idx] + redscr[544 + idx];
                        int col = nc0 + lm;
                        v += P.mob[col];
                        P.zz[(r0 + 4 * kh + j) * 256 + col] = f2bf(v);
                    }
                }
            }
            grid.sync();
        }
    }

    // final: out = [h_v|h_t] @ (late0@late1) + folded bias   (t=24 wrote hv1/ht1)
    if (b == 0) {
        int r = tid;
        float a0 = P.fb[0], a1 = P.fb[1];
        for (int k = 0; k < 256; ++k) {
            float h = bf2f(P.hv1[r * 256 + k]);
            a0 += h * P.FW[k * 2];
            a1 += h * P.FW[k * 2 + 1];
        }
        for (int k = 0; k < 256; ++k) {
            float h = bf2f(P.ht1[r * 256 + k]);
            a0 += h * P.FW[(256 + k) * 2];
            a1 += h * P.FW[(256 + k) * 2 + 1];
        }
        P.out[r * 2] = a0;
        P.out[r * 2 + 1] = a1;
    }
}

// ---------------- host ----------------

extern "C" void kernel_launch(void* const* d_in, const int* in_sizes, int n_in,
                              void* d_out, int out_size, void* d_ws, size_t ws_size,
                              hipStream_t stream) {
    (void)in_sizes; (void)n_in; (void)out_size; (void)ws_size;
    const float* x_v  = (const float*)d_in[0];
    const float* x_t  = (const float*)d_in[1];
    const float* fc0w = (const float*)d_in[2];
    const float* fc0b = (const float*)d_in[3];
    const float* fc1w = (const float*)d_in[4];
    const float* fc1b = (const float*)d_in[5];
    const float* lvW = (const float*)d_in[6];
    const float* lvU = (const float*)d_in[7];
    const float* lvV = (const float*)d_in[8];
    const float* lvb = (const float*)d_in[9];
    const float* ltW = (const float*)d_in[10];
    const float* ltU = (const float*)d_in[11];
    const float* ltV = (const float*)d_in[12];
    const float* ltb = (const float*)d_in[13];
    const float* attw = (const float*)d_in[14];
    const float* attb = (const float*)d_in[15];
    const float* rvw = (const float*)d_in[16];
    const float* rvb = (const float*)d_in[17];
    const float* rtw = (const float*)d_in[18];
    const float* rtb = (const float*)d_in[19];
    const float* mow = (const float*)d_in[20];
    const float* mob = (const float*)d_in[21];
    const float* l0w = (const float*)d_in[22];
    const float* l0b = (const float*)d_in[23];
    const float* l1w = (const float*)d_in[24];
    const float* l1b = (const float*)d_in[25];

    char* ws = (char*)d_ws;
    size_t o = 0;
    auto alloc = [&](size_t n) { size_t r = o; o += (n + 255) & ~(size_t)255; return r; };
    size_t o_xv  = alloc(6400ull * 256 * 2);
    size_t o_xt  = alloc(6400ull * 256 * 2);
    size_t o_Wxv = alloc(6400ull * 1024 * 2);
    size_t o_Wxt = alloc(6400ull * 1024 * 2);
    size_t o_f0T = alloc(256ull * 2048 * 2);
    size_t o_f1T = alloc(256ull * 2048 * 2);
    size_t o_UV  = alloc(2048ull * 512 * 2);
    size_t o_Wpv = alloc(1024ull * 256 * 2);
    size_t o_Wpt = alloc(1024ull * 256 * 2);
    size_t o_bpv = alloc(1024 * 4);
    size_t o_bpt = alloc(1024 * 4);
    size_t o_attT = alloc(2048ull * 512 * 2);
    size_t o_redT = alloc(512ull * 1024 * 2);
    size_t o_mabT = alloc(256ull * 512 * 2);
    size_t o_FW  = alloc(1024 * 4);
    size_t o_fb  = alloc(256);
    size_t o_eh  = alloc(256ull * 2048 * 2);
    size_t o_rvt = alloc(256ull * 512 * 2);
    size_t o_ps  = alloc(64ull * 256 * 4);
    size_t o_cv  = alloc(256ull * 256 * 4);
    size_t o_ct  = alloc(256ull * 256 * 4);
    size_t o_hv0 = alloc(256ull * 256 * 2);
    size_t o_hv1 = alloc(256ull * 256 * 2);
    size_t o_ht0 = alloc(256ull * 256 * 2);
    size_t o_ht1 = alloc(256ull * 256 * 2);
    size_t o_zz  = alloc(256ull * 256 * 2);
    size_t zero_bytes = o - o_cv;

    dim3 blk(256);
    prep_transpose<<<dim3(512), blk, 0, stream>>>(fc0w, (u16*)(ws + o_f0T), 11, 256);
    prep_transpose<<<dim3(512), blk, 0, stream>>>(fc1w, (u16*)(ws + o_f1T), 11, 256);
    prep_transpose<<<dim3(512), blk, 0, stream>>>(attw, (u16*)(ws + o_attT), 9, 2048);
    prep_transpose<<<dim3(256), blk, 0, stream>>>(rvw, (u16*)(ws + o_redT), 10, 256);
    prep_transpose<<<dim3(256), blk, 0, stream>>>(rtw, (u16*)(ws + o_redT) + 256 * 1024, 10, 256);
    prep_transpose<<<dim3(128), blk, 0, stream>>>(mow, (u16*)(ws + o_mabT), 9, 256);
    prep_uvpack<<<dim3(512), blk, 0, stream>>>(lvU, lvV, (u16*)(ws + o_UV));
    prep_uvpack<<<dim3(512), blk, 0, stream>>>(ltU, ltV, (u16*)(ws + o_UV) + 1024 * 512);
    prep_wpack<<<dim3(256), blk, 0, stream>>>(lvW, lvb, (u16*)(ws + o_Wpv), (float*)(ws + o_bpv));
    prep_wpack<<<dim3(256), blk, 0, stream>>>(ltW, ltb, (u16*)(ws + o_Wpt), (float*)(ws + o_bpt));
    prep_final<<<dim3(1), blk, 0, stream>>>(l0w, l0b, l1w, l1b, (float*)(ws + o_FW), (float*)(ws + o_fb));
    gemm_g1<<<dim3(100, 2, 2), blk, 0, stream>>>(x_v, x_t, (u16*)(ws + o_f0T), (u16*)(ws + o_f1T),
                                                 fc0b, fc1b, (u16*)(ws + o_xv), (u16*)(ws + o_xt));
    gemm_g2<<<dim3(100, 8, 2), blk, 0, stream>>>((u16*)(ws + o_xv), (u16*)(ws + o_xt),
                                                 (u16*)(ws + o_Wpv), (u16*)(ws + o_Wpt),
                                                 (float*)(ws + o_bpv), (float*)(ws + o_bpt),
                                                 (u16*)(ws + o_Wxv), (u16*)(ws + o_Wxt));
    hipMemsetAsync(ws + o_cv, 0, zero_bytes, stream);

    MarnArgs ma;
    ma.Wxv = (const u16*)(ws + o_Wxv);
    ma.Wxt = (const u16*)(ws + o_Wxt);
    ma.UVpk = (const u16*)(ws + o_UV);
    ma.attT = (const u16*)(ws + o_attT);
    ma.redT = (const u16*)(ws + o_redT);
    ma.mabT = (const u16*)(ws + o_mabT);
    ma.att_b = attb; ma.rvb = rvb; ma.rtb = rtb; ma.mob = mob;
    ma.FW = (const float*)(ws + o_FW);
    ma.fb = (const float*)(ws + o_fb);
    ma.cv = (float*)(ws + o_cv);
    ma.ct = (float*)(ws + o_ct);
    ma.psum = (float*)(ws + o_ps);
    ma.hv0 = (u16*)(ws + o_hv0);
    ma.hv1 = (u16*)(ws + o_hv1);
    ma.ht0 = (u16*)(ws + o_ht0);
    ma.ht1 = (u16*)(ws + o_ht1);
    ma.zz = (u16*)(ws + o_zz);
    ma.eh = (u16*)(ws + o_eh);
    ma.rvt = (u16*)(ws + o_rvt);
    ma.out = (float*)d_out;
    void* kargs[] = { &ma };
    hipLaunchCooperativeKernel((void*)marn_recur, dim3(256), dim3(256), kargs, 0, stream);
}

// Round 3
// 1748.840 us; speedup vs baseline: 2.5072x; 2.5072x over previous
//
#include <hip/hip_runtime.h>

typedef unsigned short u16;
typedef unsigned int u32;
typedef unsigned long long u64;
using bfrag = __attribute__((ext_vector_type(8))) short;   // 8 bf16 (4 VGPRs)
using facc  = __attribute__((ext_vector_type(4))) float;   // MFMA accumulator

#define DEV __device__ __forceinline__
#define AGT __HIP_MEMORY_SCOPE_AGENT

// ---- workspace layout (constexpr, shared host/device) ----
static constexpr size_t o_xv  = 0;                       // 6400*256 bf16
static constexpr size_t o_xt  = 3276800;
static constexpr size_t o_Wxv = 6553600;                 // 6400*1024 bf16
static constexpr size_t o_Wxt = 19660800;
static constexpr size_t o_f0T = 32768000;                // 256*2048 bf16
static constexpr size_t o_f1T = 33816576;
static constexpr size_t o_UV  = 34865152;                // 2048*512 bf16 (lv then lt)
static constexpr size_t o_Wpv = 36962304;                // 1024*256 bf16
static constexpr size_t o_Wpt = 37486592;
static constexpr size_t o_bpv = 38010880;                // 1024 f32
static constexpr size_t o_bpt = 38014976;
static constexpr size_t o_attT= 38019072;                // 2048*512 bf16
static constexpr size_t o_redT= 40116224;                // 512*1024 bf16
static constexpr size_t o_mabT= 41164800;                // 256*512 bf16
static constexpr size_t o_FW  = 41426944;                // 512*2 f32
static constexpr size_t o_fb  = 41431040;                // 2 f32
static constexpr size_t o_eh  = 41431296;                // 256*2048 bf16
static constexpr size_t o_rvt = 42479872;                // 256*512 bf16
static constexpr size_t o_ps  = 42742016;                // 64*256 f32
static constexpr size_t o_hv0 = 42807552;                // 256*256 bf16 each
static constexpr size_t o_hv1 = 42938624;
static constexpr size_t o_ht0 = 43069696;
static constexpr size_t o_ht1 = 43200768;
static constexpr size_t o_zz  = 43331840;
static constexpr size_t o_bar = 43462912;                // barrier counters
static constexpr size_t o_end = 43463936;

DEV u16 f2bf(float f) {
    u32 u = __float_as_uint(f);
    u32 r = (u + 0x7FFFu + ((u >> 16) & 1u)) >> 16;   // RNE
    return (u16)r;
}
DEV float bf2f(u16 h) { return __uint_as_float(((u32)h) << 16); }
DEV u32 pk2(float a, float b) { return (u32)f2bf(a) | ((u32)f2bf(b) << 16); }
DEV float sigm(float x) { return 1.0f / (1.0f + __expf(-x)); }
DEV float tanh2(float x) { return 2.0f * sigm(2.0f * x) - 1.0f; }  // overflow-safe tanh
DEV facc mfma16(bfrag a, bfrag b, facc c) {
    return __builtin_amdgcn_mfma_f32_16x16x32_bf16(a, b, c, 0, 0, 0);
}

// ---- coherent loads: relaxed agent-scope atomic loads (L3-direct) ----
DEV u64 ld64c(const void* p) { return __hip_atomic_load((u64*)p, __ATOMIC_RELAXED, AGT); }
DEV uint4 ld_c16(const void* p) {
    u64 a = ld64c(p), b = ld64c((const char*)p + 8);
    uint4 r; r.x = (u32)a; r.y = (u32)(a >> 32); r.z = (u32)b; r.w = (u32)(b >> 32); return r;
}
DEV float ldf32c(const float* p) {
    return __uint_as_float(__hip_atomic_load((u32*)p, __ATOMIC_RELAXED, AGT));
}
// ---- coherent stores: no-return atomic swaps (RMW executes at L3 coherence point) ----
DEV void sw32(void* p, u32 v) { (void)__hip_atomic_exchange((u32*)p, v, __ATOMIC_RELAXED, AGT); }
DEV void sw64(void* p, u64 v) { (void)__hip_atomic_exchange((u64*)p, v, __ATOMIC_RELAXED, AGT); }
DEV void sw128(void* p, uint4 v) {
    sw64(p, ((u64)v.y << 32) | v.x);
    sw64((char*)p + 8, ((u64)v.w << 32) | v.z);
}
DEV void swf32(float* p, float v) { sw32(p, __float_as_uint(v)); }

// ---- grid barrier: tree of relaxed agent atomics + release fence ----
DEV void gbar(u32* bar, int bid, u32 k) {
    asm volatile("s_waitcnt vmcnt(0)" ::: "memory");   // every wave drains its own RMWs
    __syncthreads();
    if (threadIdx.x == 0) {
        __builtin_amdgcn_fence(__ATOMIC_RELEASE, "agent");
        u32 old = __hip_atomic_fetch_add(&bar[(bid & 7) * 16], 1u, __ATOMIC_RELAXED, AGT);
        if (old == k * 32u - 1u)
            __hip_atomic_fetch_add(&bar[128], 1u, __ATOMIC_RELAXED, AGT);
        while (__hip_atomic_load(&bar[128], __ATOMIC_RELAXED, AGT) < k * 8u)
            __builtin_amdgcn_s_sleep(2);
    }
    __syncthreads();
}

// ---------------- prep helpers (all writes via swaps) ----------------

DEV void prep_T(const float* __restrict__ src, u16* dst, int lgK, int N, int nb, int bl, int tid) {
    int pairs = ((1 << lgK) * N) >> 1;
    int kmask = (1 << lgK) - 1;
    for (int idx = bl * 256 + tid; idx < pairs; idx += nb * 256) {
        int i = idx * 2;
        int n = i >> lgK, k = i & kmask;
        sw32(dst + i, pk2(src[(size_t)k * N + n], src[(size_t)(k + 1) * N + n]));
    }
}

DEV void prep_UV(const float* U, const float* V, u16* dst, int nb, int bl, int tid) {
    for (int idx = bl * 256 + tid; idx < 262144; idx += nb * 256) {
        int i = idx * 2;
        int p = i >> 9, k = i & 511;
        int j = p >> 2, g = p & 3;
        float v0 = (k < 256) ? U[(size_t)k * 1024 + g * 256 + j] : V[(size_t)(k - 256) * 1024 + g * 256 + j];
        float v1 = (k + 1 < 256) ? U[(size_t)(k + 1) * 1024 + g * 256 + j] : V[(size_t)(k - 255) * 1024 + g * 256 + j];
        sw32(dst + i, pk2(v0, v1));
    }
}

DEV void prep_W(const float* W, const float* bsrc, u16* dst, float* bpk, int nb, int bl, int tid) {
    for (int idx = bl * 256 + tid; idx < 131072; idx += nb * 256) {
        int i = idx * 2;
        int p = i >> 8, k = i & 255;
        int j = p >> 2, g = p & 3;
        sw32(dst + i, pk2(W[(size_t)k * 1024 + g * 256 + j], W[(size_t)(k + 1) * 1024 + g * 256 + j]));
        if (k == 0) swf32(&bpk[p], bsrc[g * 256 + j]);
    }
}

DEV void prep_FW(const float* l0w, const float* l0b, const float* l1w, const float* l1b,
                 float* FW, float* fb, int tid) {
    for (int idx = tid; idx < 1024; idx += 256) {
        int k = idx >> 1, c = idx & 1;
        float a = 0.f;
        for (int j = 0; j < 256; ++j) a += l0w[k * 256 + j] * l1w[j * 2 + c];
        swf32(&FW[idx], a);
    }
    if (tid < 2) {
        float a = l1b[tid];
        for (int j = 0; j < 256; ++j) a += l0b[j] * l1w[j * 2 + tid];
        swf32(&fb[tid], a);
    }
}

// ---------------- args: 26 input ptrs + ws + out = 224 B kernarg ----------------
struct KP { const float* in[26]; char* ws; float* out; };

// ---------------- the one persistent kernel ----------------

__global__ __launch_bounds__(256) void marn_all(KP P) {
    __shared__ __align__(16) unsigned char SM[31744];
    int tid = threadIdx.x, b = blockIdx.x;
    int w = tid >> 6, l = tid & 63, lm = l & 15, kh = l >> 4;
    u32 bk = 0;
    char* ws = P.ws;

    u16* f0T = (u16*)(ws + o_f0T);
    u16* f1T = (u16*)(ws + o_f1T);
    u16* attT = (u16*)(ws + o_attT);
    u16* redT = (u16*)(ws + o_redT);
    u16* mabT = (u16*)(ws + o_mabT);
    u16* UVpk = (u16*)(ws + o_UV);
    u16* Wpv = (u16*)(ws + o_Wpv);
    u16* Wpt = (u16*)(ws + o_Wpt);
    float* bpv = (float*)(ws + o_bpv);
    float* bpt = (float*)(ws + o_bpt);
    float* FW = (float*)(ws + o_FW);
    float* fb = (float*)(ws + o_fb);
    u16* xv = (u16*)(ws + o_xv);
    u16* xt = (u16*)(ws + o_xt);
    u16* Wxv = (u16*)(ws + o_Wxv);
    u16* Wxt = (u16*)(ws + o_Wxt);
    u16* eh = (u16*)(ws + o_eh);
    u16* rvt = (u16*)(ws + o_rvt);
    u16* hv0 = (u16*)(ws + o_hv0);
    u16* hv1 = (u16*)(ws + o_hv1);
    u16* ht0 = (u16*)(ws + o_ht0);
    u16* ht1 = (u16*)(ws + o_ht1);
    u16* zz = (u16*)(ws + o_zz);
    float* psum = (float*)(ws + o_ps);
    u32* bar = (u32*)(ws + o_bar);
    const float* attb = P.in[15];
    const float* rvb = P.in[17];
    const float* rtb = P.in[19];
    const float* mob = P.in[21];

    // ======== stage 0: weight prep ========
    if      (b < 32)  prep_T(P.in[2], f0T, 11, 256, 32, b, tid);
    else if (b < 64)  prep_T(P.in[4], f1T, 11, 256, 32, b - 32, tid);
    else if (b < 128) prep_T(P.in[14], attT, 9, 2048, 64, b - 64, tid);
    else if (b < 144) prep_T(P.in[16], redT, 10, 256, 16, b - 128, tid);
    else if (b < 160) prep_T(P.in[18], redT + 256 * 1024, 10, 256, 16, b - 144, tid);
    else if (b < 168) prep_T(P.in[20], mabT, 9, 256, 8, b - 160, tid);
    else if (b < 200) prep_UV(P.in[7], P.in[8], UVpk, 32, b - 168, tid);
    else if (b < 232) prep_UV(P.in[11], P.in[12], UVpk + 1024 * 512, 32, b - 200, tid);
    else if (b < 244) prep_W(P.in[6], P.in[9], Wpv, bpv, 12, b - 232, tid);
    else if (b < 255) prep_W(P.in[10], P.in[13], Wpt, bpt, 11, b - 244, tid);
    else              prep_FW(P.in[22], P.in[23], P.in[24], P.in[25], FW, fb, tid);
    gbar(bar, b, ++bk);

    // ======== stage 1: G1  xv/xt = x @ fc^T + b ========
    {
        u16* Al = (u16*)SM;              // [64][72]
        u16* Bl = (u16*)(SM + 9216);     // [128][72]
        u16* Lt = (u16*)SM;              // [64][128] epilogue tile (aliases)
        for (int u = b; u < 400; u += 256) {
            int zs = u & 1, ny = (u >> 1) & 1, mx = u >> 2;
            const float* A = zs ? P.in[1] : P.in[0];
            const u16* BT = zs ? f1T : f0T;
            const float* bias = zs ? P.in[5] : P.in[3];
            u16* C = zs ? xt : xv;
            int m0 = mx * 64, n0 = ny * 128;
            int arow = tid >> 2, aseg = tid & 3;
            int brow = tid >> 1, bseg = tid & 1;
            facc acc[8];
#pragma unroll
            for (int i = 0; i < 8; ++i) acc[i] = (facc){0.f, 0.f, 0.f, 0.f};
            for (int c = 0; c < 32; ++c) {
                float4 av[4];
#pragma unroll
                for (int uu = 0; uu < 4; ++uu)
                    av[uu] = *(const float4*)&A[(size_t)(m0 + arow) * 2048 + c * 64 + aseg * 16 + uu * 4];
                uint4 bv[4];
#pragma unroll
                for (int uu = 0; uu < 4; ++uu)
                    bv[uu] = *(const uint4*)&BT[(size_t)(n0 + brow) * 2048 + c * 64 + bseg * 32 + uu * 8];
                __syncthreads();
                u32 pk[8];
#pragma unroll
                for (int uu = 0; uu < 4; ++uu) {
                    pk[2 * uu] = pk2(av[uu].x, av[uu].y);
                    pk[2 * uu + 1] = pk2(av[uu].z, av[uu].w);
                }
                *(uint4*)&Al[arow * 72 + aseg * 16] = make_uint4(pk[0], pk[1], pk[2], pk[3]);
                *(uint4*)&Al[arow * 72 + aseg * 16 + 8] = make_uint4(pk[4], pk[5], pk[6], pk[7]);
#pragma unroll
                for (int uu = 0; uu < 4; ++uu)
                    *(uint4*)&Bl[brow * 72 + bseg * 32 + uu * 8] = bv[uu];
                __syncthreads();
#pragma unroll
                for (int ks = 0; ks < 2; ++ks) {
                    bfrag a = *(const bfrag*)&Al[(16 * w + lm) * 72 + ks * 32 + kh * 8];
#pragma unroll
                    for (int tt = 0; tt < 8; ++tt) {
                        bfrag bb = *(const bfrag*)&Bl[(tt * 16 + lm) * 72 + ks * 32 + kh * 8];
                        acc[tt] = mfma16(a, bb, acc[tt]);
                    }
                }
            }
            __syncthreads();
#pragma unroll
            for (int tt = 0; tt < 8; ++tt)
#pragma unroll
                for (int j = 0; j < 4; ++j)
                    Lt[(16 * w + 4 * kh + j) * 128 + tt * 16 + lm] = f2bf(acc[tt][j] + bias[n0 + tt * 16 + lm]);
            __syncthreads();
            {
                int mloc = tid >> 2, seg = tid & 3;
                const uint4* lp = (const uint4*)&Lt[mloc * 128 + seg * 32];
                sw128(&C[(size_t)(m0 + mloc) * 256 + n0 + seg * 32], lp[0]);
                sw128(&C[(size_t)(m0 + mloc) * 256 + n0 + seg * 32 + 8], lp[1]);
                sw128(&C[(size_t)(m0 + mloc) * 256 + n0 + seg * 32 + 16], lp[2]);
                sw128(&C[(size_t)(m0 + mloc) * 256 + n0 + seg * 32 + 24], lp[3]);
            }
            __syncthreads();
        }
    }
    gbar(bar, b, ++bk);

    // ======== stage 2: G2  Wx = xv @ Wpk^T + bpk (row remap b*25+t -> t*256+b) ========
    {
        u16* Al = (u16*)SM;
        u16* Bl = (u16*)(SM + 9216);
        u16* Lt = (u16*)SM;
        for (int u = b; u < 1600; u += 256) {
            int mx = u >> 4, rem = u & 15;
            int ny = rem >> 1, zs = rem & 1;
            const u16* A = zs ? xt : xv;
            const u16* BT = zs ? Wpt : Wpv;
            const float* bpk = zs ? bpt : bpv;
            u16* O = zs ? Wxt : Wxv;
            int m0 = mx * 64, n0 = ny * 128;
            int arow = tid >> 2, aseg = tid & 3;
            int brow = tid >> 1, bseg = tid & 1;
            facc acc[8];
#pragma unroll
            for (int i = 0; i < 8; ++i) acc[i] = (facc){0.f, 0.f, 0.f, 0.f};
            for (int c = 0; c < 4; ++c) {
                uint4 av[2];
#pragma unroll
                for (int uu = 0; uu < 2; ++uu)
                    av[uu] = *(const uint4*)&A[(size_t)(m0 + arow) * 256 + c * 64 + aseg * 16 + uu * 8];
                uint4 bv[4];
#pragma unroll
                for (int uu = 0; uu < 4; ++uu)
                    bv[uu] = *(const uint4*)&BT[(size_t)(n0 + brow) * 256 + c * 64 + bseg * 32 + uu * 8];
                __syncthreads();
#pragma unroll
                for (int uu = 0; uu < 2; ++uu)
                    *(uint4*)&Al[arow * 72 + aseg * 16 + uu * 8] = av[uu];
#pragma unroll
                for (int uu = 0; uu < 4; ++uu)
                    *(uint4*)&Bl[brow * 72 + bseg * 32 + uu * 8] = bv[uu];
                __syncthreads();
#pragma unroll
                for (int ks = 0; ks < 2; ++ks) {
                    bfrag a = *(const bfrag*)&Al[(16 * w + lm) * 72 + ks * 32 + kh * 8];
#pragma unroll
                    for (int tt = 0; tt < 8; ++tt) {
                        bfrag bb = *(const bfrag*)&Bl[(tt * 16 + lm) * 72 + ks * 32 + kh * 8];
                        acc[tt] = mfma16(a, bb, acc[tt]);
                    }
                }
            }
            __syncthreads();
#pragma unroll
            for (int tt = 0; tt < 8; ++tt)
#pragma unroll
                for (int j = 0; j < 4; ++j)
                    Lt[(16 * w + 4 * kh + j) * 128 + tt * 16 + lm] = f2bf(acc[tt][j] + bpk[n0 + tt * 16 + lm]);
            __syncthreads();
            {
                int mloc = tid >> 2, seg = tid & 3;
                int mg = m0 + mloc;
                int bi = mg / 25, ti = mg - bi * 25;
                const uint4* lp = (const uint4*)&Lt[mloc * 128 + seg * 32];
                sw128(&O[(size_t)(ti * 256 + bi) * 1024 + n0 + seg * 32], lp[0]);
                sw128(&O[(size_t)(ti * 256 + bi) * 1024 + n0 + seg * 32 + 8], lp[1]);
                sw128(&O[(size_t)(ti * 256 + bi) * 1024 + n0 + seg * 32 + 16], lp[2]);
                sw128(&O[(size_t)(ti * 256 + bi) * 1024 + n0 + seg * 32 + 24], lp[3]);
            }
            __syncthreads();
        }
    }
    gbar(bar, b, ++bk);

    // ======== stage 3: recurrence, 25 steps ========
    u16* Al = (u16*)SM;                       // [64][136]
    u16* Bl = (u16*)(SM + 17408);             // [32][136]
    float* sscr = (float*)SM;                 // [64][33] (aliases Al)
    float* ppart = (float*)(SM + 26112);      // 256 f32
    float* sinvl = (float*)(SM + 27136);      // 16 f32
    float* redscr = (float*)(SM + 27200);     // 4*16*17 f32
    float creg[2] = {0.f, 0.f};               // this thread's two c elements

    for (int t = 0; t < 25; ++t) {
        const u16* hvp = (t & 1) ? hv1 : hv0;
        const u16* htp = (t & 1) ? ht1 : ht0;
        u16* hvc = (t & 1) ? hv0 : hv1;
        u16* htc = (t & 1) ? ht0 : ht1;

        {   // ---- P1: s = Wx[t] + h@U + z@V -> gates -> c,h ----
            int m = b >> 6, n = b & 63;
            int r0 = m * 64, p0 = n * 32;
            bool sv = (n < 32);
            const u16* hsrc = sv ? hvp : htp;
            int arow = tid >> 2, aseg = tid & 3;
            int brow = tid >> 3, bseg = tid & 7;
            uint4 ar[2][4], br[2][2];
#pragma unroll
            for (int u = 0; u < 4; ++u)
                ar[0][u] = ld_c16(&hsrc[(r0 + arow) * 256 + aseg * 32 + u * 8]);
#pragma unroll
            for (int u = 0; u < 2; ++u)
                br[0][u] = *(const uint4*)&UVpk[(p0 + brow) * 512 + bseg * 16 + u * 8];
            facc acc0 = (facc){0.f, 0.f, 0.f, 0.f}, acc1 = (facc){0.f, 0.f, 0.f, 0.f};
#pragma unroll
            for (int c = 0; c < 4; ++c) {
                int cb = c & 1;
                __syncthreads();
#pragma unroll
                for (int u = 0; u < 4; ++u)
                    *(uint4*)&Al[arow * 136 + aseg * 32 + u * 8] = ar[cb][u];
#pragma unroll
                for (int u = 0; u < 2; ++u)
                    *(uint4*)&Bl[brow * 136 + bseg * 16 + u * 8] = br[cb][u];
                __syncthreads();
                if (c < 3) {
                    int cn = c + 1, nb = cb ^ 1;
                    const u16* asrc = (cn < 2) ? hsrc : zz;
                    int koff = (cn & 1) * 128;
#pragma unroll
                    for (int u = 0; u < 4; ++u)
                        ar[nb][u] = ld_c16(&asrc[(r0 + arow) * 256 + koff + aseg * 32 + u * 8]);
#pragma unroll
                    for (int u = 0; u < 2; ++u)
                        br[nb][u] = *(const uint4*)&UVpk[(p0 + brow) * 512 + cn * 128 + bseg * 16 + u * 8];
                }
#pragma unroll
                for (int ks = 0; ks < 4; ++ks) {
                    bfrag a = *(const bfrag*)&Al[(16 * w + lm) * 136 + ks * 32 + kh * 8];
                    bfrag b0 = *(const bfrag*)&Bl[lm * 136 + ks * 32 + kh * 8];
                    bfrag b1 = *(const bfrag*)&Bl[(16 + lm) * 136 + ks * 32 + kh * 8];
                    acc0 = mfma16(a, b0, acc0);
                    acc1 = mfma16(a, b1, acc1);
                }
            }
            __syncthreads();
#pragma unroll
            for (int j = 0; j < 4; ++j) {
                sscr[(16 * w + 4 * kh + j) * 33 + lm] = acc0[j];
                sscr[(16 * w + 4 * kh + j) * 33 + 16 + lm] = acc1[j];
            }
            __syncthreads();
            const u16* wxs = sv ? Wxv : Wxt;
            u16* hw = sv ? hvc : htc;
            int pl0 = sv ? p0 : (p0 - 1024);
            int r = tid >> 2, jp = tid & 3;
            uint4 wx4 = *(const uint4*)&wxs[(size_t)(t * 256 + r0 + r) * 1024 + pl0 + jp * 8];
            const u16* wxp = (const u16*)&wx4;
            float h2[2];
#pragma unroll
            for (int e = 0; e < 2; ++e) {
                int p = jp * 8 + e * 4;
                float s0 = sscr[r * 33 + p + 0] + bf2f(wxp[e * 4 + 0]);
                float s1 = sscr[r * 33 + p + 1] + bf2f(wxp[e * 4 + 1]);
                float s2 = sscr[r * 33 + p + 2] + bf2f(wxp[e * 4 + 2]);
                float s3 = sscr[r * 33 + p + 3] + bf2f(wxp[e * 4 + 3]);
                float fg = sigm(s0), ig = sigm(s1), og = sigm(s2), ch = tanh2(s3);
                float cn = fg * creg[e] + ig * ch;
                creg[e] = cn;
                h2[e] = tanh2(cn) * og;
            }
            sw32(&hw[(r0 + r) * 256 + (pl0 >> 2) + jp * 2], pk2(h2[0], h2[1]));
        }
        gbar(bar, b, ++bk);

        if (t < 24) {
            {   // ---- P2: exp-logits (att), row-sums, eh = e * h_concat ----
                int m = b >> 6, n = b & 63;
                int r0 = m * 64, c0 = n * 32;
                int arow = tid >> 2, aseg = tid & 3;
                int brow = tid >> 3, bseg = tid & 7;
                uint4 ar[2][4], br[2][2];
#pragma unroll
                for (int u = 0; u < 4; ++u)
                    ar[0][u] = ld_c16(&hvc[(r0 + arow) * 256 + aseg * 32 + u * 8]);
#pragma unroll
                for (int u = 0; u < 2; ++u)
                    br[0][u] = *(const uint4*)&attT[(c0 + brow) * 512 + bseg * 16 + u * 8];
                facc acc0 = (facc){0.f, 0.f, 0.f, 0.f}, acc1 = (facc){0.f, 0.f, 0.f, 0.f};
#pragma unroll
                for (int c = 0; c < 4; ++c) {
                    int cb = c & 1;
                    __syncthreads();
#pragma unroll
                    for (int u = 0; u < 4; ++u)
                        *(uint4*)&Al[arow * 136 + aseg * 32 + u * 8] = ar[cb][u];
#pragma unroll
                    for (int u = 0; u < 2; ++u)
                        *(uint4*)&Bl[brow * 136 + bseg * 16 + u * 8] = br[cb][u];
                    __syncthreads();
                    if (c < 3) {
                        int cn = c + 1, nb = cb ^ 1;
                        const u16* asrc = (cn < 2) ? hvc : htc;
                        int koff = (cn & 1) * 128;
#pragma unroll
                        for (int u = 0; u < 4; ++u)
                            ar[nb][u] = ld_c16(&asrc[(r0 + arow) * 256 + koff + aseg * 32 + u * 8]);
#pragma unroll
                        for (int u = 0; u < 2; ++u)
                            br[nb][u] = *(const uint4*)&attT[(c0 + brow) * 512 + cn * 128 + bseg * 16 + u * 8];
                    }
#pragma unroll
                    for (int ks = 0; ks < 4; ++ks) {
                        bfrag a = *(const bfrag*)&Al[(16 * w + lm) * 136 + ks * 32 + kh * 8];
                        bfrag b0 = *(const bfrag*)&Bl[lm * 136 + ks * 32 + kh * 8];
                        bfrag b1 = *(const bfrag*)&Bl[(16 + lm) * 136 + ks * 32 + kh * 8];
                        acc0 = mfma16(a, b0, acc0);
                        acc1 = mfma16(a, b1, acc1);
                    }
                }
                __syncthreads();
#pragma unroll
                for (int j = 0; j < 4; ++j) {
                    sscr[(16 * w + 4 * kh + j) * 33 + lm] = acc0[j];
                    sscr[(16 * w + 4 * kh + j) * 33 + 16 + lm] = acc1[j];
                }
                __syncthreads();
                int r = tid >> 2, q = tid & 3;
                int n15 = n & 15;
                const u16* hfs = (n15 < 8) ? hvc : htc;
                int hc0 = (32 * n15) & 255;
                uint4 hfv = ld_c16(&hfs[(r0 + r) * 256 + hc0 + q * 8]);
                const u16* hfp = (const u16*)&hfv;
                float ps = 0.f;
                u32 pk[4];
#pragma unroll
                for (int x = 0; x < 4; ++x) {
                    float e0 = __expf(sscr[r * 33 + q * 8 + 2 * x] + attb[c0 + q * 8 + 2 * x]);
                    float e1 = __expf(sscr[r * 33 + q * 8 + 2 * x + 1] + attb[c0 + q * 8 + 2 * x + 1]);
                    ps += e0 + e1;
                    pk[x] = (u32)f2bf(e0 * bf2f(hfp[2 * x])) | ((u32)f2bf(e1 * bf2f(hfp[2 * x + 1])) << 16);
                }
                sw64(&eh[(size_t)(r0 + r) * 2048 + c0 + q * 8], ((u64)pk[1] << 32) | pk[0]);
                sw64(&eh[(size_t)(r0 + r) * 2048 + c0 + q * 8 + 4], ((u64)pk[3] << 32) | pk[2]);
                ppart[r * 4 + q] = ps;
                __syncthreads();
                if (tid < 64) {
                    float s = ppart[tid * 4] + ppart[tid * 4 + 1] + ppart[tid * 4 + 2] + ppart[tid * 4 + 3];
                    swf32(&psum[n * 256 + r0 + tid], s);
                }
            }
            gbar(bar, b, ++bk);

            {   // ---- P3: rv|rt = relu(sinv * (eh @ redT) + bias) ----
                int m = b >> 4, n = b & 15;
                int r0 = m * 16, nc0 = n * 32;
                int half = (n < 8) ? 0 : 1;
                if (tid < 64) {
                    int r = tid >> 2, q = tid & 3;
                    float s = 0.f;
                    for (int j2 = q * 16; j2 < q * 16 + 16; ++j2) s += ldf32c(&psum[j2 * 256 + r0 + r]);
                    ppart[r * 4 + q] = s;
                }
                __syncthreads();
                if (tid < 16)
                    sinvl[tid] = 1.0f / (ppart[tid * 4] + ppart[tid * 4 + 1] + ppart[tid * 4 + 2] + ppart[tid * 4 + 3]);
                int arow = tid >> 4, aseg = tid & 15;
                int brow = tid >> 3, bseg = tid & 7;
                uint4 ar[2], br[2][2];
                ar[0] = ld_c16(&eh[(size_t)(r0 + arow) * 2048 + half * 256 + aseg * 8]);
#pragma unroll
                for (int u = 0; u < 2; ++u)
                    br[0][u] = *(const uint4*)&redT[(nc0 + brow) * 1024 + bseg * 16 + u * 8];
                int tt = w & 1, kh2 = w >> 1;
                facc acc = (facc){0.f, 0.f, 0.f, 0.f};
#pragma unroll
                for (int c = 0; c < 8; ++c) {
                    int cb = c & 1;
                    __syncthreads();
                    *(uint4*)&Al[arow * 136 + aseg * 8] = ar[cb];
#pragma unroll
                    for (int u = 0; u < 2; ++u)
                        *(uint4*)&Bl[brow * 136 + bseg * 16 + u * 8] = br[cb][u];
                    __syncthreads();
                    if (c < 7) {
                        int cn = c + 1, nb = cb ^ 1;
                        ar[nb] = ld_c16(&eh[(size_t)(r0 + arow) * 2048 + (cn >> 1) * 512 + half * 256 + (cn & 1) * 128 + aseg * 8]);
#pragma unroll
                        for (int u = 0; u < 2; ++u)
                            br[nb][u] = *(const uint4*)&redT[(nc0 + brow) * 1024 + cn * 128 + bseg * 16 + u * 8];
                    }
#pragma unroll
                    for (int k2 = 0; k2 < 2; ++k2) {
                        int ks = kh2 * 2 + k2;
                        bfrag a = *(const bfrag*)&Al[lm * 136 + ks * 32 + kh * 8];
                        bfrag bb = *(const bfrag*)&Bl[(tt * 16 + lm) * 136 + ks * 32 + kh * 8];
                        acc = mfma16(a, bb, acc);
                    }
                }
                __syncthreads();
                if (w >= 2) {
#pragma unroll
                    for (int j = 0; j < 4; ++j)
                        redscr[tt * 272 + (4 * kh + j) * 17 + lm] = acc[j];
                }
                __syncthreads();
                if (w < 2) {
#pragma unroll
                    for (int j = 0; j < 4; ++j) {
                        float v = acc[j] + redscr[tt * 272 + (4 * kh + j) * 17 + lm];
                        int rloc = 4 * kh + j;
                        int col = nc0 + tt * 16 + lm;
                        float bs = (col < 256) ? rvb[col] : rtb[col - 256];
                        v = fmaxf(sinvl[rloc] * v + bs, 0.0f);
                        sscr[rloc * 33 + tt * 16 + lm] = v;
                    }
                }
                __syncthreads();
                {
                    int rloc = tid >> 4, cp = tid & 15;
                    sw32(&rvt[(r0 + rloc) * 512 + nc0 + 2 * cp],
                         pk2(sscr[rloc * 33 + 2 * cp], sscr[rloc * 33 + 2 * cp + 1]));
                }
            }
            gbar(bar, b, ++bk);

            {   // ---- P4: z = [rv|rt] @ mab_out + b ----
                int m = b >> 4, n = b & 15;
                int r0 = m * 16, nc0 = n * 16;
                int arow = tid >> 4, aseg = tid & 15;
                uint4 ar[2], br[2];
                ar[0] = ld_c16(&rvt[(r0 + arow) * 512 + aseg * 8]);
                br[0] = *(const uint4*)&mabT[(nc0 + arow) * 512 + aseg * 8];
                facc acc = (facc){0.f, 0.f, 0.f, 0.f};
#pragma unroll
                for (int c = 0; c < 4; ++c) {
                    int cb = c & 1;
                    __syncthreads();
                    *(uint4*)&Al[arow * 136 + aseg * 8] = ar[cb];
                    *(uint4*)&Bl[arow * 136 + aseg * 8] = br[cb];
                    __syncthreads();
                    if (c < 3) {
                        ar[cb ^ 1] = ld_c16(&rvt[(r0 + arow) * 512 + (c + 1) * 128 + aseg * 8]);
                        br[cb ^ 1] = *(const uint4*)&mabT[(nc0 + arow) * 512 + (c + 1) * 128 + aseg * 8];
                    }
                    bfrag a = *(const bfrag*)&Al[lm * 136 + w * 32 + kh * 8];
                    bfrag bb = *(const bfrag*)&Bl[lm * 136 + w * 32 + kh * 8];
                    acc = mfma16(a, bb, acc);
                }
                __syncthreads();
                if (w > 0) {
#pragma unroll
                    for (int j = 0; j < 4; ++j)
                        redscr[(w - 1) * 272 + (4 * kh + j) * 17 + lm] = acc[j];
                }
                __syncthreads();
                if (w == 0) {
#pragma unroll
                    for (int j = 0; j < 4; ++j) {
                        int idx = (4 * kh + j) * 17 + lm;
                        float v = acc[j] + redscr[idx] + redscr[272 + idx] + redscr[544 + idx] + mob[nc0 + lm];
                        sscr[(4 * kh + j) * 33 + lm] = v;
                    }
                }
                __syncthreads();
                if (tid < 128) {
                    int rloc = tid >> 3, cp = tid & 7;
                    sw32(&zz[(r0 + rloc) * 256 + nc0 + 2 * cp],
                         pk2(sscr[rloc * 33 + 2 * cp], sscr[rloc * 33 + 2 * cp + 1]));
                }
            }
            gbar(bar, b, ++bk);
        }
    }

    // ======== final: out[b] = [h_v|h_t] @ (late0@late1) + folded bias ========
    {
        if (tid < 64) {
            float a0 = 0.f, a1 = 0.f;
            u64 hv = ld64c(&hv1[b * 256 + tid * 4]);
            u64 ht = ld64c(&ht1[b * 256 + tid * 4]);
#pragma unroll
            for (int i = 0; i < 4; ++i) {
                int k = tid * 4 + i;
                float h0 = bf2f((u16)(hv >> (16 * i)));
                float h1 = bf2f((u16)(ht >> (16 * i)));
                a0 += h0 * FW[k * 2] + h1 * FW[(256 + k) * 2];
                a1 += h0 * FW[k * 2 + 1] + h1 * FW[(256 + k) * 2 + 1];
            }
            ppart[tid] = a0;
            ppart[64 + tid] = a1;
        }
        __syncthreads();
        if (tid < 2) {
            float s = ldf32c(&fb[tid]);
            for (int i = 0; i < 64; ++i) s += ppart[tid * 64 + i];
            P.out[b * 2 + tid] = s;
        }
    }
}

// ---------------- host ----------------

extern "C" void kernel_launch(void* const* d_in, const int* in_sizes, int n_in,
                              void* d_out, int out_size, void* d_ws, size_t ws_size,
                              hipStream_t stream) {
    (void)in_sizes; (void)n_in; (void)out_size; (void)ws_size;
    KP P;
    for (int i = 0; i < 26; ++i) P.in[i] = (const float*)d_in[i];
    P.ws = (char*)d_ws;
    P.out = (float*)d_out;

    hipMemsetAsync((char*)d_ws + o_hv0, 0, o_end - o_hv0, stream);

    void* kargs[] = { &P };
    hipError_t e = hipLaunchCooperativeKernel((void*)marn_all, dim3(256), dim3(256),
                                              kargs, 0, stream);
    if (e != hipSuccess) {
        (void)hipGetLastError();   // clear sticky error; fall back to plain launch
        marn_all<<<dim3(256), dim3(256), 0, stream>>>(P);
    }
}